// Round 1
// baseline (180.339 us; speedup 1.0000x reference)
//
#include <hip/hip_runtime.h>

typedef _Float16 f16_t;
typedef __attribute__((ext_vector_type(8))) _Float16 f16x8;
typedef __attribute__((ext_vector_type(4))) _Float16 f16x4;
typedef __attribute__((ext_vector_type(4))) float f32x4;

#define MFMA16(a, b, c) __builtin_amdgcn_mfma_f32_16x16x32_f16((a), (b), (c), 0, 0, 0)

// Problem constants: EMB=1024, KDIM=64, B=8, S=2048, rows = B*S = 16384.

// ---------------------------------------------------------------------------
// prep: transpose/convert weights to fp16.
// WT[j][n][e] = w_j[e][n]  (j: 0=q,1=k,2=v1), with 1/sqrt(64)=0.125 folded into w_q.
// WV2T[e][k]  = w_v2[k][e]
// ---------------------------------------------------------------------------
extern "C" __global__ __launch_bounds__(256) void prep_k(
    const float* __restrict__ wq, const float* __restrict__ wk,
    const float* __restrict__ wv1, const float* __restrict__ wv2,
    f16_t* __restrict__ WT, f16_t* __restrict__ WV2T) {
  int idx = blockIdx.x * 256 + threadIdx.x;  // 0..262143
  if (idx < 196608) {
    int j = idx >> 16;
    int r = idx & 65535;
    int n = r >> 10;
    int e = r & 1023;
    const float* w = (j == 0) ? wq : ((j == 1) ? wk : wv1);
    float v = w[e * 64 + n];
    if (j == 0) v *= 0.125f;
    WT[idx] = (f16_t)v;
  } else if (idx < 262144) {
    int r = idx - 196608;
    int e = r >> 6, k = r & 63;
    WV2T[r] = (f16_t)wv2[k * 1024 + e];
  }
}

// ---------------------------------------------------------------------------
// proj: QKV = x @ [wq|wk|wv1]  ([16384,1024] @ [1024,192]), fp16 MFMA.
// Block: 64 rows x 192 cols. Wave w covers all 4 m-tiles x n-tiles [3w..3w+2].
// Q,K written row-major [row][64]; V written transposed Vtg[b][64][2048].
// Double-buffered (register-prefetch) staging of x (with fp32->fp16 convert)
// and WT into LDS.
// ---------------------------------------------------------------------------
extern "C" __global__ __launch_bounds__(256) void proj_k(
    const float* __restrict__ x, const f16_t* __restrict__ WT,
    f16_t* __restrict__ Qg, f16_t* __restrict__ Kg, f16_t* __restrict__ Vtg) {
  __shared__ __align__(16) f16_t xs[64][72];    // x tile, +8 pad (2-way max)
  __shared__ __align__(16) f16_t wsh[192][72];  // W tile
  const int t = threadIdx.x;
  const int wave = t >> 6, lane = t & 63;
  const int quad = lane >> 4, ln = lane & 15;
  const int r0 = blockIdx.x * 64;

  f32x4 acc[4][3];
#pragma unroll
  for (int mt = 0; mt < 4; ++mt)
#pragma unroll
    for (int nn = 0; nn < 3; ++nn) acc[mt][nn] = (f32x4){0.f, 0.f, 0.f, 0.f};

  float4 xreg[4];
  f16x8 wreg[6];
  // prefetch chunk 0
#pragma unroll
  for (int i = 0; i < 4; ++i) {
    int flat = t + i * 256;
    int row = flat >> 4, c4 = (flat & 15) * 4;
    xreg[i] = *(const float4*)&x[(size_t)(r0 + row) * 1024 + c4];
  }
#pragma unroll
  for (int i = 0; i < 6; ++i) {
    int flat = t + i * 256;
    int row = flat >> 3, c8 = (flat & 7) * 8;
    wreg[i] = *(const f16x8*)&WT[row * 1024 + c8];
  }

  for (int ec = 0; ec < 16; ++ec) {
    __syncthreads();  // previous compute done with LDS
#pragma unroll
    for (int i = 0; i < 4; ++i) {
      int flat = t + i * 256;
      int row = flat >> 4, c4 = (flat & 15) * 4;
      f16x4 h;
      h[0] = (f16_t)xreg[i].x; h[1] = (f16_t)xreg[i].y;
      h[2] = (f16_t)xreg[i].z; h[3] = (f16_t)xreg[i].w;
      *(f16x4*)&xs[row][c4] = h;
    }
#pragma unroll
    for (int i = 0; i < 6; ++i) {
      int flat = t + i * 256;
      int row = flat >> 3, c8 = (flat & 7) * 8;
      *(f16x8*)&wsh[row][c8] = wreg[i];
    }
    __syncthreads();
    if (ec < 15) {  // prefetch next chunk while computing this one
      int e0 = (ec + 1) * 64;
#pragma unroll
      for (int i = 0; i < 4; ++i) {
        int flat = t + i * 256;
        int row = flat >> 4, c4 = (flat & 15) * 4;
        xreg[i] = *(const float4*)&x[(size_t)(r0 + row) * 1024 + e0 + c4];
      }
#pragma unroll
      for (int i = 0; i < 6; ++i) {
        int flat = t + i * 256;
        int row = flat >> 3, c8 = (flat & 7) * 8;
        wreg[i] = *(const f16x8*)&WT[row * 1024 + e0 + c8];
      }
    }
    // A-frags: A[m=ln][k=quad*8+j], two k-halves
    f16x8 a0[4], a1[4];
#pragma unroll
    for (int mt = 0; mt < 4; ++mt) {
      a0[mt] = *(const f16x8*)&xs[mt * 16 + ln][quad * 8];
      a1[mt] = *(const f16x8*)&xs[mt * 16 + ln][32 + quad * 8];
    }
#pragma unroll
    for (int nn = 0; nn < 3; ++nn) {
      int nb = (wave * 3 + nn) * 16;
      f16x8 b0 = *(const f16x8*)&wsh[nb + ln][quad * 8];
      f16x8 b1 = *(const f16x8*)&wsh[nb + ln][32 + quad * 8];
#pragma unroll
      for (int mt = 0; mt < 4; ++mt) {
        acc[mt][nn] = MFMA16(a0[mt], b0, acc[mt][nn]);
        acc[mt][nn] = MFMA16(a1[mt], b1, acc[mt][nn]);
      }
    }
  }

  // Epilogue. C/D layout: row = quad*4 + reg, col = ln.
  __syncthreads();                // xs reuse as V-transpose buffer
  f16_t* vt = &xs[0][0];          // [64 v][72] (stride 72)
#pragma unroll
  for (int nn = 0; nn < 3; ++nn) {
    int col = (wave * 3 + nn) * 16 + ln;
    int j = col >> 6, cc = col & 63;  // j uniform per (wave,nn)
#pragma unroll
    for (int mt = 0; mt < 4; ++mt)
#pragma unroll
      for (int r = 0; r < 4; ++r) {
        int row = mt * 16 + quad * 4 + r;  // local 0..63
        f16_t hv = (f16_t)acc[mt][nn][r];
        if (j == 0)      Qg[(size_t)(r0 + row) * 64 + cc] = hv;
        else if (j == 1) Kg[(size_t)(r0 + row) * 64 + cc] = hv;
        else             vt[cc * 72 + row] = hv;
      }
  }
  __syncthreads();
  {  // coalesced write of the transposed V chunk
    int bb = r0 >> 11, sblk = r0 & 2047;
#pragma unroll
    for (int i = 0; i < 2; ++i) {
      int flat = t + i * 256;
      int vrow = flat >> 3, c8 = (flat & 7) * 8;
      *(f16x8*)&Vtg[((size_t)bb * 64 + vrow) * 2048 + sblk + c8] =
          *(const f16x8*)&vt[vrow * 72 + c8];
    }
  }
}

// ---------------------------------------------------------------------------
// flash: causal online-softmax attention, O1 = softmax(Q K^T) V1.
// 1 block = (batch b, 64-row q-tile). Wave w owns q rows [q0+16w, q0+16w+16).
// s-tiles of 64, K staged row-major, V staged from Vtg (already [v][s]).
// P goes C-layout -> LDS -> A-layout for the PV MFMA.
// ---------------------------------------------------------------------------
extern "C" __global__ __launch_bounds__(256) void flash_k(
    const f16_t* __restrict__ Qg, const f16_t* __restrict__ Kg,
    const f16_t* __restrict__ Vtg, f16_t* __restrict__ O1) {
  __shared__ __align__(16) f16_t Ks[64][72];      // [s][feat]
  __shared__ __align__(16) f16_t Vs[64][72];      // [v][s]
  __shared__ __align__(16) f16_t Ps[4][16][72];   // per-wave P tile [q][s]
  const int t = threadIdx.x;
  const int wave = t >> 6, lane = t & 63;
  const int quad = lane >> 4, ln = lane & 15;
  const int b = blockIdx.x >> 5, qt = blockIdx.x & 31;
  const int q0 = qt * 64;
  const size_t rbase = (size_t)b * 2048;

  f16x8 qa0, qa1;
  {
    size_t row = rbase + q0 + wave * 16 + ln;
    qa0 = *(const f16x8*)&Qg[row * 64 + quad * 8];
    qa1 = *(const f16x8*)&Qg[row * 64 + 32 + quad * 8];
  }
  float m[4], lsum[4];
  f32x4 oacc[4];
#pragma unroll
  for (int r = 0; r < 4; ++r) { m[r] = -__builtin_inff(); lsum[r] = 0.f; }
#pragma unroll
  for (int nt = 0; nt < 4; ++nt) oacc[nt] = (f32x4){0.f, 0.f, 0.f, 0.f};

  f16x8 kreg[2], vreg[2];
#pragma unroll
  for (int i = 0; i < 2; ++i) {  // prefetch s-tile 0
    int flat = t + i * 256;
    int row = flat >> 3, c8 = (flat & 7) * 8;
    kreg[i] = *(const f16x8*)&Kg[(rbase + row) * 64 + c8];
    vreg[i] = *(const f16x8*)&Vtg[((size_t)b * 64 + row) * 2048 + c8];
  }

  for (int st = 0; st <= qt; ++st) {
    __syncthreads();
#pragma unroll
    for (int i = 0; i < 2; ++i) {
      int flat = t + i * 256;
      int row = flat >> 3, c8 = (flat & 7) * 8;
      *(f16x8*)&Ks[row][c8] = kreg[i];
      *(f16x8*)&Vs[row][c8] = vreg[i];
    }
    __syncthreads();
    if (st < qt) {  // prefetch next tile during compute
      int s0n = (st + 1) * 64;
#pragma unroll
      for (int i = 0; i < 2; ++i) {
        int flat = t + i * 256;
        int row = flat >> 3, c8 = (flat & 7) * 8;
        kreg[i] = *(const f16x8*)&Kg[(rbase + s0n + row) * 64 + c8];
        vreg[i] = *(const f16x8*)&Vtg[((size_t)b * 64 + row) * 2048 + s0n + c8];
      }
    }
    // scores: C[q_local][s_local], q rows of this wave
    f32x4 sc[4];
#pragma unroll
    for (int nt = 0; nt < 4; ++nt) {
      f16x8 b0 = *(const f16x8*)&Ks[nt * 16 + ln][quad * 8];
      f16x8 b1 = *(const f16x8*)&Ks[nt * 16 + ln][32 + quad * 8];
      f32x4 c = (f32x4){0.f, 0.f, 0.f, 0.f};
      c = MFMA16(qa0, b0, c);
      c = MFMA16(qa1, b1, c);
      sc[nt] = c;
    }
    if (st == qt) {  // causal mask, diagonal tile only (s0 == q0)
#pragma unroll
      for (int nt = 0; nt < 4; ++nt)
#pragma unroll
        for (int r = 0; r < 4; ++r)
          if (nt * 16 + ln > wave * 16 + quad * 4 + r) sc[nt][r] = -__builtin_inff();
    }
    // online softmax; row r lives on the 16 lanes of this quad
    float alpha[4], mn[4];
#pragma unroll
    for (int r = 0; r < 4; ++r) {
      float mx = fmaxf(fmaxf(sc[0][r], sc[1][r]), fmaxf(sc[2][r], sc[3][r]));
      mx = fmaxf(mx, __shfl_xor(mx, 1, 64));
      mx = fmaxf(mx, __shfl_xor(mx, 2, 64));
      mx = fmaxf(mx, __shfl_xor(mx, 4, 64));
      mx = fmaxf(mx, __shfl_xor(mx, 8, 64));
      mn[r] = fmaxf(m[r], mx);
      alpha[r] = __expf(m[r] - mn[r]);  // m=-inf, mn finite -> 0: ok
      m[r] = mn[r];
    }
    float p[4][4];
#pragma unroll
    for (int nt = 0; nt < 4; ++nt)
#pragma unroll
      for (int r = 0; r < 4; ++r) p[nt][r] = __expf(sc[nt][r] - mn[r]);
#pragma unroll
    for (int r = 0; r < 4; ++r) {
      float s = (p[0][r] + p[1][r]) + (p[2][r] + p[3][r]);
      s += __shfl_xor(s, 1, 64);
      s += __shfl_xor(s, 2, 64);
      s += __shfl_xor(s, 4, 64);
      s += __shfl_xor(s, 8, 64);
      lsum[r] = lsum[r] * alpha[r] + s;
    }
#pragma unroll
    for (int nt = 0; nt < 4; ++nt)
#pragma unroll
      for (int r = 0; r < 4; ++r) oacc[nt][r] *= alpha[r];
    // P: C-layout -> LDS -> A-layout (same wave, in-order DS ops)
#pragma unroll
    for (int nt = 0; nt < 4; ++nt)
#pragma unroll
      for (int r = 0; r < 4; ++r)
        Ps[wave][quad * 4 + r][nt * 16 + ln] = (f16_t)p[nt][r];
    f16x8 pa0 = *(const f16x8*)&Ps[wave][ln][quad * 8];
    f16x8 pa1 = *(const f16x8*)&Ps[wave][ln][32 + quad * 8];
#pragma unroll
    for (int nt = 0; nt < 4; ++nt) {
      f16x8 v0 = *(const f16x8*)&Vs[nt * 16 + ln][quad * 8];
      f16x8 v1 = *(const f16x8*)&Vs[nt * 16 + ln][32 + quad * 8];
      oacc[nt] = MFMA16(pa0, v0, oacc[nt]);
      oacc[nt] = MFMA16(pa1, v1, oacc[nt]);
    }
  }
  float inv[4];
#pragma unroll
  for (int r = 0; r < 4; ++r) inv[r] = 1.0f / lsum[r];
#pragma unroll
  for (int nt = 0; nt < 4; ++nt)
#pragma unroll
    for (int r = 0; r < 4; ++r) {
      size_t row = rbase + q0 + wave * 16 + quad * 4 + r;
      O1[row * 64 + nt * 16 + ln] = (f16_t)(oacc[nt][r] * inv[r]);
    }
}

// ---------------------------------------------------------------------------
// fproj: out = O1 @ w_v2  ([16384,64] @ [64,1024]), fp32 out. Write-bound.
// Block: 64 rows; wave w covers cols [256w, 256w+256).
// ---------------------------------------------------------------------------
extern "C" __global__ __launch_bounds__(256) void fproj_k(
    const f16_t* __restrict__ O1, const f16_t* __restrict__ WV2T,
    float* __restrict__ out) {
  const int t = threadIdx.x;
  const int wave = t >> 6, lane = t & 63;
  const int quad = lane >> 4, ln = lane & 15;
  const int r0 = blockIdx.x * 64;
  f16x8 a0[4], a1[4];
#pragma unroll
  for (int mt = 0; mt < 4; ++mt) {
    size_t row = (size_t)(r0 + mt * 16 + ln);
    a0[mt] = *(const f16x8*)&O1[row * 64 + quad * 8];
    a1[mt] = *(const f16x8*)&O1[row * 64 + 32 + quad * 8];
  }
#pragma unroll 4
  for (int nt = 0; nt < 16; ++nt) {
    int eb = wave * 256 + nt * 16;
    f16x8 b0 = *(const f16x8*)&WV2T[(eb + ln) * 64 + quad * 8];
    f16x8 b1 = *(const f16x8*)&WV2T[(eb + ln) * 64 + 32 + quad * 8];
#pragma unroll
    for (int mt = 0; mt < 4; ++mt) {
      f32x4 c = (f32x4){0.f, 0.f, 0.f, 0.f};
      c = MFMA16(a0[mt], b0, c);
      c = MFMA16(a1[mt], b1, c);
#pragma unroll
      for (int r = 0; r < 4; ++r)
        out[(size_t)(r0 + mt * 16 + quad * 4 + r) * 1024 + eb + ln] = c[r];
    }
  }
}

// ---------------------------------------------------------------------------
extern "C" void kernel_launch(void* const* d_in, const int* in_sizes, int n_in,
                              void* d_out, int out_size, void* d_ws, size_t ws_size,
                              hipStream_t stream) {
  const float* x   = (const float*)d_in[0];
  const float* wq  = (const float*)d_in[1];
  const float* wk  = (const float*)d_in[2];
  const float* wv1 = (const float*)d_in[3];
  const float* wv2 = (const float*)d_in[4];
  float* out = (float*)d_out;

  // workspace layout (f16 elements), total ~8.5 MiB
  f16_t* WT   = (f16_t*)d_ws;        // [3][64][1024]   = 196608
  f16_t* WV2T = WT + 196608;         // [1024][64]      = 65536
  f16_t* Qg   = WV2T + 65536;        // [16384][64]     (scale folded in)
  f16_t* Kg   = Qg + 1048576;        // [16384][64]
  f16_t* Vtg  = Kg + 1048576;        // [8][64][2048]   (V transposed)
  f16_t* O1   = Vtg + 1048576;       // [16384][64]

  prep_k <<<1024, 256, 0, stream>>>(wq, wk, wv1, wv2, WT, WV2T);
  proj_k <<<256, 256, 0, stream>>>(x, WT, Qg, Kg, Vtg);
  flash_k<<<256, 256, 0, stream>>>(Qg, Kg, Vtg, O1);
  fproj_k<<<256, 256, 0, stream>>>(O1, WV2T, out);
}

// Round 2
// 178.424 us; speedup vs baseline: 1.0107x; 1.0107x over previous
//
#include <hip/hip_runtime.h>

typedef _Float16 f16_t;
typedef __attribute__((ext_vector_type(8))) _Float16 f16x8;
typedef __attribute__((ext_vector_type(4))) _Float16 f16x4;
typedef __attribute__((ext_vector_type(4))) float f32x4;

#define MFMA16(a, b, c) __builtin_amdgcn_mfma_f32_16x16x32_f16((a), (b), (c), 0, 0, 0)

// Problem constants: EMB=1024, KDIM=64, B=8, S=2048, rows = B*S = 16384.

// ---------------------------------------------------------------------------
// prep: transpose/convert weights to fp16.
// WT[j][n][e] = w_j[e][n]  (j: 0=q,1=k,2=v1), 0.125 scale folded into w_q.
// WV2T[e][k]  = w_v2[k][e]
// ---------------------------------------------------------------------------
extern "C" __global__ __launch_bounds__(256) void prep_k(
    const float* __restrict__ wq, const float* __restrict__ wk,
    const float* __restrict__ wv1, const float* __restrict__ wv2,
    f16_t* __restrict__ WT, f16_t* __restrict__ WV2T) {
  int idx = blockIdx.x * 256 + threadIdx.x;  // 0..262143
  if (idx < 196608) {
    int j = idx >> 16;
    int r = idx & 65535;
    int n = r >> 10;
    int e = r & 1023;
    const float* w = (j == 0) ? wq : ((j == 1) ? wk : wv1);
    float v = w[e * 64 + n];
    if (j == 0) v *= 0.125f;
    WT[idx] = (f16_t)v;
  } else if (idx < 262144) {
    int r = idx - 196608;
    int e = r >> 6, k = r & 63;
    WV2T[r] = (f16_t)wv2[k * 1024 + e];
  }
}

// ---------------------------------------------------------------------------
// proj: QKV = x @ [wq|wk|wv1]  ([16384,1024] @ [1024,192]), fp16 MFMA.
// Block: 32 rows x 192 cols (512 blocks -> 2 blocks/CU, 8 waves/CU).
// Q,K row-major [row][64]; V transposed Vtg[b][64][2048].
// ---------------------------------------------------------------------------
extern "C" __global__ __launch_bounds__(256) void proj_k(
    const float* __restrict__ x, const f16_t* __restrict__ WT,
    f16_t* __restrict__ Qg, f16_t* __restrict__ Kg, f16_t* __restrict__ Vtg) {
  __shared__ __align__(16) f16_t xs[32][72];    // x tile
  __shared__ __align__(16) f16_t wsh[192][72];  // W tile (reused for V transpose)
  const int t = threadIdx.x;
  const int wave = t >> 6, lane = t & 63;
  const int quad = lane >> 4, ln = lane & 15;
  const int r0 = blockIdx.x * 32;

  f32x4 acc[2][3];
#pragma unroll
  for (int mt = 0; mt < 2; ++mt)
#pragma unroll
    for (int nn = 0; nn < 3; ++nn) acc[mt][nn] = (f32x4){0.f, 0.f, 0.f, 0.f};

  float4 xreg[2];
  f16x8 wreg[6];
  // prefetch chunk 0
#pragma unroll
  for (int i = 0; i < 2; ++i) {
    int flat = t + i * 256;
    int row = flat >> 4, c4 = (flat & 15) * 4;
    xreg[i] = *(const float4*)&x[(size_t)(r0 + row) * 1024 + c4];
  }
#pragma unroll
  for (int i = 0; i < 6; ++i) {
    int flat = t + i * 256;
    int row = flat >> 3, c8 = (flat & 7) * 8;
    wreg[i] = *(const f16x8*)&WT[row * 1024 + c8];
  }

  for (int ec = 0; ec < 16; ++ec) {
    __syncthreads();
#pragma unroll
    for (int i = 0; i < 2; ++i) {
      int flat = t + i * 256;
      int row = flat >> 4, c4 = (flat & 15) * 4;
      f16x4 h;
      h[0] = (f16_t)xreg[i].x; h[1] = (f16_t)xreg[i].y;
      h[2] = (f16_t)xreg[i].z; h[3] = (f16_t)xreg[i].w;
      *(f16x4*)&xs[row][c4] = h;
    }
#pragma unroll
    for (int i = 0; i < 6; ++i) {
      int flat = t + i * 256;
      int row = flat >> 3, c8 = (flat & 7) * 8;
      *(f16x8*)&wsh[row][c8] = wreg[i];
    }
    __syncthreads();
    if (ec < 15) {
      int e0 = (ec + 1) * 64;
#pragma unroll
      for (int i = 0; i < 2; ++i) {
        int flat = t + i * 256;
        int row = flat >> 4, c4 = (flat & 15) * 4;
        xreg[i] = *(const float4*)&x[(size_t)(r0 + row) * 1024 + e0 + c4];
      }
#pragma unroll
      for (int i = 0; i < 6; ++i) {
        int flat = t + i * 256;
        int row = flat >> 3, c8 = (flat & 7) * 8;
        wreg[i] = *(const f16x8*)&WT[row * 1024 + e0 + c8];
      }
    }
    f16x8 a0[2], a1[2];
#pragma unroll
    for (int mt = 0; mt < 2; ++mt) {
      a0[mt] = *(const f16x8*)&xs[mt * 16 + ln][quad * 8];
      a1[mt] = *(const f16x8*)&xs[mt * 16 + ln][32 + quad * 8];
    }
#pragma unroll
    for (int nn = 0; nn < 3; ++nn) {
      int nb = (wave * 3 + nn) * 16;
      f16x8 b0 = *(const f16x8*)&wsh[nb + ln][quad * 8];
      f16x8 b1 = *(const f16x8*)&wsh[nb + ln][32 + quad * 8];
#pragma unroll
      for (int mt = 0; mt < 2; ++mt) {
        acc[mt][nn] = MFMA16(a0[mt], b0, acc[mt][nn]);
        acc[mt][nn] = MFMA16(a1[mt], b1, acc[mt][nn]);
      }
    }
  }

  // Epilogue. C/D layout: row = quad*4 + reg, col = ln.
  __syncthreads();                 // wsh reuse as V-transpose buffer
  f16_t* vt = &wsh[0][0];          // [64 v][stride 40] rows 0..31
#pragma unroll
  for (int nn = 0; nn < 3; ++nn) {
    int col = (wave * 3 + nn) * 16 + ln;
    int j = col >> 6, cc = col & 63;  // j uniform per (wave,nn)
#pragma unroll
    for (int mt = 0; mt < 2; ++mt)
#pragma unroll
      for (int r = 0; r < 4; ++r) {
        int row = mt * 16 + quad * 4 + r;  // local 0..31
        f16_t hv = (f16_t)acc[mt][nn][r];
        if (j == 0)      Qg[(size_t)(r0 + row) * 64 + cc] = hv;
        else if (j == 1) Kg[(size_t)(r0 + row) * 64 + cc] = hv;
        else             vt[cc * 40 + row] = hv;
      }
  }
  __syncthreads();
  {  // coalesced write of the transposed V chunk (64 v x 32 s)
    int bb = r0 >> 11, sblk = r0 & 2047;
    int vrow = t >> 2, c8 = (t & 3) * 8;
    *(f16x8*)&Vtg[((size_t)bb * 64 + vrow) * 2048 + sblk + c8] =
        *(const f16x8*)&vt[vrow * 40 + c8];
  }
}

// ---------------------------------------------------------------------------
// flash: causal online-softmax attention, split-s (flash-decoding style).
// Grid 1024: blockIdx = b*128 + qt*4 + c. Block handles q-tile qt (64 rows)
// over s-tiles [8c, min(8c+7, qt)]. Writes unnormalized Opart (f16) + m,l.
// Wave w owns q rows [q0+16w, q0+16w+16).
// ---------------------------------------------------------------------------
extern "C" __global__ __launch_bounds__(256) void flash_k(
    const f16_t* __restrict__ Qg, const f16_t* __restrict__ Kg,
    const f16_t* __restrict__ Vtg, f16_t* __restrict__ Opart,
    float* __restrict__ Mpart, float* __restrict__ Lpart) {
  const int bi = blockIdx.x;
  const int b = bi >> 7, qt = (bi >> 2) & 31, c = bi & 3;
  const int st0 = c * 8;
  if (st0 > qt) return;  // empty chunk (merge_k never reads it)
  const int stEnd = (qt < st0 + 7) ? qt : (st0 + 7);

  __shared__ __align__(16) f16_t Ks[64][72];      // [s][feat]
  __shared__ __align__(16) f16_t Vs[64][72];      // [v][s]
  __shared__ __align__(16) f16_t Ps[4][16][72];   // per-wave P tile [q][s]
  const int t = threadIdx.x;
  const int wave = t >> 6, lane = t & 63;
  const int quad = lane >> 4, ln = lane & 15;
  const int q0 = qt * 64;
  const size_t rbase = (size_t)b * 2048;

  f16x8 qa0, qa1;
  {
    size_t row = rbase + q0 + wave * 16 + ln;
    qa0 = *(const f16x8*)&Qg[row * 64 + quad * 8];
    qa1 = *(const f16x8*)&Qg[row * 64 + 32 + quad * 8];
  }
  float m[4], lsum[4];
  f32x4 oacc[4];
#pragma unroll
  for (int r = 0; r < 4; ++r) { m[r] = -__builtin_inff(); lsum[r] = 0.f; }
#pragma unroll
  for (int nt = 0; nt < 4; ++nt) oacc[nt] = (f32x4){0.f, 0.f, 0.f, 0.f};

  f16x8 kreg[2], vreg[2];
#pragma unroll
  for (int i = 0; i < 2; ++i) {  // prefetch s-tile st0
    int flat = t + i * 256;
    int row = flat >> 3, c8 = (flat & 7) * 8;
    kreg[i] = *(const f16x8*)&Kg[(rbase + st0 * 64 + row) * 64 + c8];
    vreg[i] = *(const f16x8*)&Vtg[((size_t)b * 64 + row) * 2048 + st0 * 64 + c8];
  }

  for (int st = st0; st <= stEnd; ++st) {
    __syncthreads();
#pragma unroll
    for (int i = 0; i < 2; ++i) {
      int flat = t + i * 256;
      int row = flat >> 3, c8 = (flat & 7) * 8;
      *(f16x8*)&Ks[row][c8] = kreg[i];
      *(f16x8*)&Vs[row][c8] = vreg[i];
    }
    __syncthreads();
    if (st < stEnd) {  // prefetch next tile during compute
      int s0n = (st + 1) * 64;
#pragma unroll
      for (int i = 0; i < 2; ++i) {
        int flat = t + i * 256;
        int row = flat >> 3, c8 = (flat & 7) * 8;
        kreg[i] = *(const f16x8*)&Kg[(rbase + s0n + row) * 64 + c8];
        vreg[i] = *(const f16x8*)&Vtg[((size_t)b * 64 + row) * 2048 + s0n + c8];
      }
    }
    // scores: C[q_local][s_local]
    f32x4 sc[4];
#pragma unroll
    for (int nt = 0; nt < 4; ++nt) {
      f16x8 b0 = *(const f16x8*)&Ks[nt * 16 + ln][quad * 8];
      f16x8 b1 = *(const f16x8*)&Ks[nt * 16 + ln][32 + quad * 8];
      f32x4 cc = (f32x4){0.f, 0.f, 0.f, 0.f};
      cc = MFMA16(qa0, b0, cc);
      cc = MFMA16(qa1, b1, cc);
      sc[nt] = cc;
    }
    if (st == qt) {  // causal mask on the diagonal tile
#pragma unroll
      for (int nt = 0; nt < 4; ++nt)
#pragma unroll
        for (int r = 0; r < 4; ++r)
          if (nt * 16 + ln > wave * 16 + quad * 4 + r) sc[nt][r] = -__builtin_inff();
    }
    // online softmax; row r lives on the 16 lanes of this quad
    float alpha[4], mn[4];
#pragma unroll
    for (int r = 0; r < 4; ++r) {
      float mx = fmaxf(fmaxf(sc[0][r], sc[1][r]), fmaxf(sc[2][r], sc[3][r]));
      mx = fmaxf(mx, __shfl_xor(mx, 1, 64));
      mx = fmaxf(mx, __shfl_xor(mx, 2, 64));
      mx = fmaxf(mx, __shfl_xor(mx, 4, 64));
      mx = fmaxf(mx, __shfl_xor(mx, 8, 64));
      mn[r] = fmaxf(m[r], mx);
      alpha[r] = __expf(m[r] - mn[r]);
      m[r] = mn[r];
    }
    float p[4][4];
#pragma unroll
    for (int nt = 0; nt < 4; ++nt)
#pragma unroll
      for (int r = 0; r < 4; ++r) p[nt][r] = __expf(sc[nt][r] - mn[r]);
#pragma unroll
    for (int r = 0; r < 4; ++r) {
      float s = (p[0][r] + p[1][r]) + (p[2][r] + p[3][r]);
      s += __shfl_xor(s, 1, 64);
      s += __shfl_xor(s, 2, 64);
      s += __shfl_xor(s, 4, 64);
      s += __shfl_xor(s, 8, 64);
      lsum[r] = lsum[r] * alpha[r] + s;
    }
#pragma unroll
    for (int nt = 0; nt < 4; ++nt)
#pragma unroll
      for (int r = 0; r < 4; ++r) oacc[nt][r] *= alpha[r];
    // P: C-layout -> LDS -> A-layout (same wave, in-order DS ops)
#pragma unroll
    for (int nt = 0; nt < 4; ++nt)
#pragma unroll
      for (int r = 0; r < 4; ++r)
        Ps[wave][quad * 4 + r][nt * 16 + ln] = (f16_t)p[nt][r];
    f16x8 pa0 = *(const f16x8*)&Ps[wave][ln][quad * 8];
    f16x8 pa1 = *(const f16x8*)&Ps[wave][ln][32 + quad * 8];
#pragma unroll
    for (int nt = 0; nt < 4; ++nt) {
      f16x8 v0 = *(const f16x8*)&Vs[nt * 16 + ln][quad * 8];
      f16x8 v1 = *(const f16x8*)&Vs[nt * 16 + ln][32 + quad * 8];
      oacc[nt] = MFMA16(pa0, v0, oacc[nt]);
      oacc[nt] = MFMA16(pa1, v1, oacc[nt]);
    }
  }
  // write unnormalized partial + m,l
  const size_t pid = (size_t)bi;
#pragma unroll
  for (int nt = 0; nt < 4; ++nt)
#pragma unroll
    for (int r = 0; r < 4; ++r) {
      int qrow = wave * 16 + quad * 4 + r;
      Opart[pid * 4096 + (size_t)qrow * 64 + nt * 16 + ln] = (f16_t)oacc[nt][r];
    }
  if (ln == 0) {
#pragma unroll
    for (int r = 0; r < 4; ++r) {
      int qrow = wave * 16 + quad * 4 + r;
      Mpart[pid * 64 + qrow] = m[r];
      Lpart[pid * 64 + qrow] = lsum[r];
    }
  }
}

// ---------------------------------------------------------------------------
// merge: combine <=4 split-s partials per (b, qt), normalize, write O1 (f16).
// Grid 256: blockIdx = b*32 + qt. Thread t: q = t>>2, v-quarter = (t&3)*16.
// ---------------------------------------------------------------------------
extern "C" __global__ __launch_bounds__(256) void merge_k(
    const f16_t* __restrict__ Opart, const float* __restrict__ Mpart,
    const float* __restrict__ Lpart, f16_t* __restrict__ O1) {
  const int t = threadIdx.x;
  const int b = blockIdx.x >> 5, qt = blockIdx.x & 31;
  const int q = t >> 2, vq = (t & 3) * 16;
  const int pbase = b * 128 + qt * 4;
  const int nc = (qt >> 3) + 1;  // non-empty chunks for this qt
  float m[4], l[4], M = -1e30f;
  for (int c = 0; c < nc; ++c) {
    m[c] = Mpart[(size_t)(pbase + c) * 64 + q];
    l[c] = Lpart[(size_t)(pbase + c) * 64 + q];
    M = fmaxf(M, m[c]);
  }
  float denom = 0.f;
  float acc[16];
#pragma unroll
  for (int k = 0; k < 16; ++k) acc[k] = 0.f;
  for (int c = 0; c < nc; ++c) {
    float w = __expf(m[c] - M);
    denom += w * l[c];
    const f16_t* src = &Opart[(size_t)(pbase + c) * 4096 + q * 64 + vq];
    f16x8 o0 = *(const f16x8*)src;
    f16x8 o1 = *(const f16x8*)(src + 8);
#pragma unroll
    for (int k = 0; k < 8; ++k) acc[k] += w * (float)o0[k];
#pragma unroll
    for (int k = 0; k < 8; ++k) acc[k + 8] += w * (float)o1[k];
  }
  float inv = 1.0f / denom;
  f16x8 r0, r1;
#pragma unroll
  for (int k = 0; k < 8; ++k) {
    r0[k] = (f16_t)(acc[k] * inv);
    r1[k] = (f16_t)(acc[k + 8] * inv);
  }
  size_t row = (size_t)b * 2048 + qt * 64 + q;
  *(f16x8*)&O1[row * 64 + vq] = r0;
  *(f16x8*)&O1[row * 64 + vq + 8] = r1;
}

// ---------------------------------------------------------------------------
// fproj: out = O1 @ w_v2  ([16384,64] @ [64,1024]), fp32 out. Write-bound.
// 512 blocks x 32 rows; wave w covers cols [256w, 256w+256).
// ---------------------------------------------------------------------------
extern "C" __global__ __launch_bounds__(256) void fproj_k(
    const f16_t* __restrict__ O1, const f16_t* __restrict__ WV2T,
    float* __restrict__ out) {
  const int t = threadIdx.x;
  const int wave = t >> 6, lane = t & 63;
  const int quad = lane >> 4, ln = lane & 15;
  const int r0 = blockIdx.x * 32;
  f16x8 a0[2], a1[2];
#pragma unroll
  for (int mt = 0; mt < 2; ++mt) {
    size_t row = (size_t)(r0 + mt * 16 + ln);
    a0[mt] = *(const f16x8*)&O1[row * 64 + quad * 8];
    a1[mt] = *(const f16x8*)&O1[row * 64 + 32 + quad * 8];
  }
#pragma unroll 4
  for (int nt = 0; nt < 16; ++nt) {
    int eb = wave * 256 + nt * 16;
    f16x8 b0 = *(const f16x8*)&WV2T[(eb + ln) * 64 + quad * 8];
    f16x8 b1 = *(const f16x8*)&WV2T[(eb + ln) * 64 + 32 + quad * 8];
#pragma unroll
    for (int mt = 0; mt < 2; ++mt) {
      f32x4 cc = (f32x4){0.f, 0.f, 0.f, 0.f};
      cc = MFMA16(a0[mt], b0, cc);
      cc = MFMA16(a1[mt], b1, cc);
#pragma unroll
      for (int r = 0; r < 4; ++r)
        out[(size_t)(r0 + mt * 16 + quad * 4 + r) * 1024 + eb + ln] = cc[r];
    }
  }
}

// ---------------------------------------------------------------------------
extern "C" void kernel_launch(void* const* d_in, const int* in_sizes, int n_in,
                              void* d_out, int out_size, void* d_ws, size_t ws_size,
                              hipStream_t stream) {
  const float* x   = (const float*)d_in[0];
  const float* wq  = (const float*)d_in[1];
  const float* wk  = (const float*)d_in[2];
  const float* wv1 = (const float*)d_in[3];
  const float* wv2 = (const float*)d_in[4];
  float* out = (float*)d_out;

  // workspace layout (f16 elements unless noted), total ~17.8 MiB
  f16_t* WT    = (f16_t*)d_ws;         // [3][64][1024]   = 196608
  f16_t* WV2T  = WT + 196608;          // [1024][64]      = 65536
  f16_t* Qg    = WV2T + 65536;         // [16384][64]
  f16_t* Kg    = Qg + 1048576;         // [16384][64]
  f16_t* Vtg   = Kg + 1048576;         // [8][64][2048]
  f16_t* O1    = Vtg + 1048576;        // [16384][64]
  f16_t* Opart = O1 + 1048576;         // [1024][64][64]  = 4194304
  float* Mpart = (float*)(Opart + 4194304);  // [1024][64]
  float* Lpart = Mpart + 65536;              // [1024][64]

  prep_k <<<1024, 256, 0, stream>>>(wq, wk, wv1, wv2, WT, WV2T);
  proj_k <<<512, 256, 0, stream>>>(x, WT, Qg, Kg, Vtg);
  flash_k<<<1024, 256, 0, stream>>>(Qg, Kg, Vtg, Opart, Mpart, Lpart);
  merge_k<<<256, 256, 0, stream>>>(Opart, Mpart, Lpart, O1);
  fproj_k<<<512, 256, 0, stream>>>(O1, WV2T, out);
}